// Round 6
// baseline (102.192 us; speedup 1.0000x reference)
//
#include <hip/hip_runtime.h>

// SimplePitchEstimator on MI355X (gfx950).
// ac = irfft(rfft(x,512)^2) == linear self-convolution c[n] = sum y[i]y[n-i],
// y = x - mean(x). Round-17 RESUBMIT (r17 bench was GPUAcquisitionTimeout —
// infra failure, kernel never ran; source identical to preserve A/B chain).
// LDS double-buffer pipeline via global_load_lds.
//
// Evidence chain: r12 = 97.17us = 2x ~42.5us harness poison fills
// (immutable) + ~12.1us kernel. r15 (pk_fma even half) -> 96.15, r16
// (dual-bank full packing) -> 95.54, both matching prediction; kernel now
// ~10.5us = 6.7 HBM + ~3.3 conv + ~0.5 phases, SERIAL. VALU packing
// exhausted; remaining gap is the serial load->conv structure.
// Failed overlap attempts: r13 s_sleep stagger (+3.9us, dispatch-mapping
// refuted), r14 register-staged 2-pass (+6.7us: per-wave vmcnt waits at
// drain, 2w/SIMD starvation, 40-VGPR bloat). This round avoids all three
// mechanisms: HBM->LDS DMA (global_load_lds, zero staging VGPRs), wait is
// the chip-wide barrier AFTER conv-0, overlap is intra-block.
// 512 blocks x 128 frames (2 chunks of 64). Per chunk each wave stages
// its 10 rows: row = 64 frames x 16B = 1024B = one wave-wide DMA
// (uniform LDS base + lane*16, per-lane global addr). Chunk-1 DMAs
// issued before conv-0, drained by the __syncthreads after it ->
// conv-0 (~1.7us chip) hides under ch1's ~3.35us drain.
// LDS 2x40960 = 81920 -> 2 blocks/CU (4x40960 exact-fit precedent),
// 8 waves/CU = 2 waves/SIMD; conv issue work per SIMD conserved
// (2 waves x 2 chunks = 4 x 1). Conv code byte-identical to r16.
// Model: 3.35 + 0.3 + max(1.7,3.35) + 0.3 + 1.7 ~= 9.0-9.7us.
// Predicted dur 95.54 -> 94.0-95.0; revert to r16 if >= 95.6.

#define SR_F    16000.0f
#define HOPSZ   256
#define TFRAMES 4096
#define SAMPLES 1048576

typedef __attribute__((ext_vector_type(2))) float f32x2;

#define CMP(v_, c_) ((c_) == 0 ? (v_).x : (c_) == 1 ? (v_).y : \
                     (c_) == 2 ? (v_).z : (v_).w)

template<int N0>
__device__ __forceinline__ void conv_tile(const float4* __restrict__ col4,
                                          const float* __restrict__ colf,
                                          float& best, int& bl) {
    constexpr int J    = 15;
    constexpr int B0   = ((N0 - 3) / 4) * 4;   // aligned window base row
    constexpr int Q0   = B0 / 4;               // base quad at round 0
    constexpr int KOFF = N0 - B0;              // 3..6
    constexpr int IC   = (N0 + J) / 2;         // i-count for max lag
    constexpr int RT   = (IC + 3) / 4;         // total rounds
    constexpr int RC   = (N0 - 6 + 7) / 8;     // clean rounds (8r+6 < N0)
    constexpr int T    = RC / 6;               // runtime x6 trips
    constexpr int R6   = 6 * T;                // first static round
    static_assert(KOFF >= 3 && KOFF + J - 1 <= 20, "window index bound");
    static_assert(RC >= 1 && RC <= RT - 1, "clean/ragged split");
    static_assert(Q0 - RT + 1 >= 0, "refill quad in range");

    // Bank A: pairs (0,1)(2,3)...(12,13) + scalar j=14  (even-parity d's)
    // Bank B: pairs (1,2)(3,4)...(13,14) + scalar j=0   (odd-parity d's)
    // final acc[j] = A[j] + B[j]; regrouping by d-parity only.
    f32x2 accA[7], accB[7];
    float accA14 = 0.f, accB0 = 0.f;
    #pragma unroll
    for (int p = 0; p < 7; ++p) { accA[p] = f32x2{0.f, 0.f};
                                  accB[p] = f32x2{0.f, 0.f}; }

    // window: quad-var vi (0..5) -> pair vars (2vi, 2vi+1)
    f32x2 P0_, P1_, P2_, P3_, P4_, P5_, P6_, P7_, P8_, P9_, P10_, P11_;
    float4 xa_, xb_;

#define PPAIR(pi_) \
    ((pi_) == 0 ? P0_ : (pi_) == 1 ? P1_ : (pi_) == 2 ? P2_ :  \
     (pi_) == 3 ? P3_ : (pi_) == 4 ? P4_ : (pi_) == 5 ? P5_ :  \
     (pi_) == 6 ? P6_ : (pi_) == 7 ? P7_ : (pi_) == 8 ? P8_ :  \
     (pi_) == 9 ? P9_ : (pi_) == 10 ? P10_ : P11_)

#define PREAD(pi_, h_) ((h_) ? PPAIR(pi_).y : PPAIR(pi_).x)

#define PST(pi_, e_) do {                                                 \
    if      ((pi_) == 0)  P0_  = (e_); else if ((pi_) == 1)  P1_  = (e_); \
    else if ((pi_) == 2)  P2_  = (e_); else if ((pi_) == 3)  P3_  = (e_); \
    else if ((pi_) == 4)  P4_  = (e_); else if ((pi_) == 5)  P5_  = (e_); \
    else if ((pi_) == 6)  P6_  = (e_); else if ((pi_) == 7)  P7_  = (e_); \
    else if ((pi_) == 8)  P8_  = (e_); else if ((pi_) == 9)  P9_  = (e_); \
    else if ((pi_) == 10) P10_ = (e_); else                  P11_ = (e_); \
    } while (0)

#define WSTORE(vi_, q_) do {                                              \
    PST(2 * (vi_),     (f32x2{(q_).x, (q_).y}));                          \
    PST(2 * (vi_) + 1, (f32x2{(q_).z, (q_).w}));                          \
    } while (0)

    // round with round-index R_ (mask/parity) and rotation phase K_ (=R_ mod 6
    // folded statically); MASKED_=1 -> ragged prune, all-scalar into bank A.
    // Clean rounds: even-parity d -> bank A pairs (g = KOFF+2p-d even);
    //               odd-parity d  -> bank B pairs (g = KOFF+2p+1-d even).
#define ROUND_BODY(K_, R_, MASKED_)                                       \
    {                                                                     \
        const float4 xc = ((R_) & 1) ? xb_ : xa_;                         \
        _Pragma("unroll")                                                 \
        for (int d = 0; d < 4; ++d) {                                     \
            const float xv = CMP(xc, d);                                  \
            if (!(MASKED_) && (((KOFF - d) & 1) == 0)) {                  \
                const f32x2 xv2 = {xv, xv};                               \
                _Pragma("unroll")                                         \
                for (int p = 0; p < 7; ++p) {                             \
                    const int g  = KOFF + 2 * p - d;       /* even */     \
                    const int vi = ((Q0 + g / 4 - (K_)) % 6 + 6) % 6;     \
                    const int pi = 2 * vi + ((g >> 1) & 1);               \
                    accA[p] = __builtin_elementwise_fma(xv2, PPAIR(pi),   \
                                                        accA[p]);         \
                }                                                         \
                {                                                         \
                    const int g  = KOFF + 14 - d;                         \
                    const int vi = ((Q0 + g / 4 - (K_)) % 6 + 6) % 6;     \
                    const int pi = 2 * vi + ((g >> 1) & 1);               \
                    accA14 = fmaf(xv, PREAD(pi, g & 1), accA14);          \
                }                                                         \
            } else if (!(MASKED_)) {                                      \
                const f32x2 xv2 = {xv, xv};                               \
                {                                                         \
                    const int g  = KOFF + 0 - d;           /* even */     \
                    const int vi = ((Q0 + g / 4 - (K_)) % 6 + 6) % 6;     \
                    const int pi = 2 * vi + ((g >> 1) & 1);               \
                    accB0 = fmaf(xv, PREAD(pi, g & 1), accB0);            \
                }                                                         \
                _Pragma("unroll")                                         \
                for (int p = 0; p < 7; ++p) {                             \
                    const int g  = KOFF + 2 * p + 1 - d;   /* even */     \
                    const int vi = ((Q0 + g / 4 - (K_)) % 6 + 6) % 6;     \
                    const int pi = 2 * vi + ((g >> 1) & 1);               \
                    accB[p] = __builtin_elementwise_fma(xv2, PPAIR(pi),   \
                                                        accB[p]);         \
                }                                                         \
            } else {                                                      \
                _Pragma("unroll")                                         \
                for (int j = 0; j < J; ++j) {                             \
                    if (8 * (R_) + 2 * d < N0 + j) {                      \
                        const int g  = KOFF + j - d;                      \
                        const int vi = ((Q0 + g / 4 - (K_)) % 6 + 6) % 6; \
                        const int pi = 2 * vi + ((g >> 1) & 1);           \
                        const float wv = PREAD(pi, g & 1);                \
                        if (j == 14)                                      \
                            accA14 = fmaf(xv, wv, accA14);                \
                        else if (j & 1)                                   \
                            accA[j >> 1].y = fmaf(xv, wv, accA[j >> 1].y);\
                        else                                              \
                            accA[j >> 1].x = fmaf(xv, wv, accA[j >> 1].x);\
                    }                                                     \
                }                                                         \
            }                                                             \
        }                                                                 \
    }

    // ---- init: quads Q0..Q0+5 into vars (Q0+i)%6 (clip quads>39), x quad 0
    #pragma unroll
    for (int i = 0; i < 6; ++i) {
        const float4 q = (Q0 + i <= 39) ? col4[(Q0 + i) * 64]
                                        : make_float4(0.f, 0.f, 0.f, 0.f);
        WSTORE((Q0 + i) % 6, q);
    }
    xa_ = col4[0];

    // ---- runtime x6 trips: rounds r = 6t+k, all clean ----
    const float4* xq = col4;                 // x base: quad 6t
    const float4* wq = col4 + Q0 * 64;       // refill base: quad Q0-6t
    #pragma unroll 1
    for (int t = 0; t < T; ++t) {
        #pragma unroll
        for (int k = 0; k < 6; ++k) {
            if (((k + 1) & 1) == 0) xa_ = xq[(k + 1) * 64];
            else                    xb_ = xq[(k + 1) * 64];
            ROUND_BODY(k, k, 0)
            // refill quad Q0-6t-k-1 -> var just freed this round
            {
                const float4 rq = wq[-(k + 1) * 64];
                WSTORE(((Q0 - k - 1) % 6 + 6) % 6, rq);
            }
        }
        xq += 6 * 64;
        wq -= 6 * 64;
    }

    // ---- static rounds rr = R6..RT-1 (clean remainder + ragged) ----
    #pragma unroll
    for (int u = 0; u < RT - R6; ++u) {
        const int rr = R6 + u;                       // constant after unroll
        if (rr + 1 < RT) {                           // compile-time guard
            if (((rr + 1) & 1) == 0) xa_ = col4[(rr + 1) * 64];
            else                     xb_ = col4[(rr + 1) * 64];
        }
        ROUND_BODY(rr, rr, (rr >= RC))
        if (rr + 1 < RT) {
            const float4 rq = col4[(Q0 - rr - 1) * 64];
            WSTORE(((Q0 - rr - 1) % 6 + 6) % 6, rq);
        }
    }

    // ---- finalize: combine banks, x2 + center term, local argmax ----
    // A[j]: j=14 -> accA14; else lane (j&1) of accA[j>>1].
    // B[j]: j=0 -> accB0; j odd -> accB[(j-1)/2].x; j even -> accB[j/2-1].y.
    #pragma unroll
    for (int j = 0; j < J; ++j) {
        const float av = (j == 14) ? accA14
                        : ((j & 1) ? accA[j >> 1].y : accA[j >> 1].x);
        const float bv2 = (j == 0) ? accB0
                        : ((j & 1) ? accB[(j - 1) >> 1].x : accB[j / 2 - 1].y);
        const float aj = av + bv2;
        float v2 = aj + aj;
        if ((N0 + j) % 2 == 0) {
            const int R = (N0 + j) / 2;              // constant after unroll
            const float c = colf[(R / 4) * 256 + (R & 3)];
            v2 = fmaf(c, c, v2);
        }
        if (v2 > best) { best = v2; bl = N0 + j; }   // strict >: first max
    }
#undef ROUND_BODY
#undef WSTORE
#undef PST
#undef PREAD
#undef PPAIR
}

// Stage one 64-frame chunk into dst: wave s DMAs rows 10s..10s+9.
// Row q = 64 frames x 16B = 1024B = one wave-wide global_load_lds:
// LDS dest = uniform &dst[q*64] + lane*16; global src per-lane
// = gs (frame base incl. lane's f*HOPSZ) + q*16B.
__device__ __forceinline__ void stage_chunk(const float* __restrict__ gs,
                                            float4* __restrict__ dst,
                                            const int s) {
    #pragma unroll
    for (int k = 0; k < 10; ++k) {
        const int q = 10 * s + k;
        __builtin_amdgcn_global_load_lds(
            (const __attribute__((address_space(1))) void*)(gs + q * 4),
            (__attribute__((address_space(3))) void*)&dst[q * 64],
            16, 0, 0);
    }
}

// Center chunk in-place: mean via aux rows (in the OTHER buffer), subtract,
// write back; pm (max|y|) returned in a register.
__device__ __forceinline__ float center_chunk(float4* __restrict__ X,
                                              float* __restrict__ aux,
                                              const int tid, const int s,
                                              const int f) {
    float4 v4[10];
    float ps = 0.f;
    #pragma unroll
    for (int k = 0; k < 10; ++k) {
        v4[k] = X[(10 * s + k) * 64 + f];
        ps += v4[k].x + v4[k].y + v4[k].z + v4[k].w;
    }
    aux[tid] = ps;
    __syncthreads();
    const float mu = (aux[f] + aux[64 + f] + aux[128 + f] + aux[192 + f])
                     * (1.0f / 160.0f);
    float pm = 0.f;
    #pragma unroll
    for (int k = 0; k < 10; ++k) {
        v4[k].x -= mu; v4[k].y -= mu; v4[k].z -= mu; v4[k].w -= mu;
        pm = fmaxf(pm, fmaxf(fmaxf(v4[k].x, -v4[k].x),
                             fmaxf(v4[k].y, -v4[k].y)));
        pm = fmaxf(pm, fmaxf(fmaxf(v4[k].z, -v4[k].z),
                             fmaxf(v4[k].w, -v4[k].w)));
    }
    #pragma unroll
    for (int k = 0; k < 10; ++k)
        X[(10 * s + k) * 64 + f] = v4[k];
    __syncthreads();   // writeback visible to all waves; aux reads done
    return pm;
}

__device__ __forceinline__ void conv_chunk(const float4* __restrict__ X,
                                           const int s, const int f,
                                           float& best, int& bl) {
    const float4* col4 = X + f;
    const float*  colf = reinterpret_cast<const float*>(X) + 4 * f;
    if      (s == 0) { conv_tile< 40>(col4, colf, best, bl);
                       conv_tile<145>(col4, colf, best, bl); }
    else if (s == 1) { conv_tile< 55>(col4, colf, best, bl);
                       conv_tile<130>(col4, colf, best, bl); }
    else if (s == 2) { conv_tile< 70>(col4, colf, best, bl);
                       conv_tile<115>(col4, colf, best, bl); }
    else             { conv_tile< 85>(col4, colf, best, bl);
                       conv_tile<100>(col4, colf, best, bl); }
}

__global__ __launch_bounds__(256)
void pitch_kernel(const float* __restrict__ audio, float* __restrict__ out) {
    __shared__ float4 XA[40 * 64];                   // chunk buffer A, 40960 B
    __shared__ float4 XB[40 * 64];                   // chunk buffer B, 40960 B

    const int tid = threadIdx.x;
    const int s   = tid >> 6;          // wave id
    const int f   = tid & 63;          // frame within chunk
    const int blk = blockIdx.x;
    const int b   = blk >> 5;          // batch row (32 blocks per batch)
    const int t0  = (blk & 31) << 7;   // first frame of block (128 frames)

    const float* g0 = audio + (size_t)b * SAMPLES + (size_t)(t0 + f) * HOPSZ;
    const float* g1 = g0 + (size_t)64 * HOPSZ;

    // ---- stage chunk 0 -> A; drain ----
    stage_chunk(g0, XA, s);
    __syncthreads();                               // ch0 resident

    // ---- center A (aux rides in B: B untouched until ch1 DMA below) ----
    const float pm0 = center_chunk(XA, reinterpret_cast<float*>(XB), tid, s, f);

    // ---- issue ch1 DMA -> B, then conv A under it ----
    stage_chunk(g1, XB, s);
    float best0 = -3.4e38f; int bl0 = 0;
    conv_chunk(XA, s, f, best0, bl0);
    __syncthreads();                               // drains ch1 DMA; A dead

    // ---- center B (aux rides in A: dead), conv B ----
    const float pm1 = center_chunk(XB, reinterpret_cast<float*>(XA), tid, s, f);
    float best1 = -3.4e38f; int bl1 = 0;
    conv_chunk(XB, s, f, best1, bl1);
    __syncthreads();                               // conv B LDS reads done

    // ---- final cross-wave argmax + silent-check, both chunks ----
    float* aux  = reinterpret_cast<float*>(XA);
    int*   auxi = reinterpret_cast<int*>(XA);
    aux [tid]        = best0;
    auxi[256  + tid] = bl0;
    aux [512  + tid] = pm0;
    aux [768  + tid] = best1;
    auxi[1024 + tid] = bl1;
    aux [1280 + tid] = pm1;
    __syncthreads();

    if (s < 2) {                                   // wave 0 -> ch0, wave 1 -> ch1
        const int base = s * 768;
        float bv = aux[base + f];
        int   L  = auxi[base + 256 + f];
        #pragma unroll
        for (int c = 1; c < 4; ++c) {
            const float vv = aux[base + c * 64 + f];
            const int   lv = auxi[base + 256 + c * 64 + f];
            if (vv > bv || (vv == bv && lv < L)) { bv = vv; L = lv; }
        }
        const float mx = fmaxf(fmaxf(aux[base + 512 + f],
                                     aux[base + 512 + 64 + f]),
                               fmaxf(aux[base + 512 + 128 + f],
                                     aux[base + 512 + 192 + f]));
        const float pitch = SR_F / (float)L;
        out[(size_t)b * TFRAMES + t0 + s * 64 + f] = (mx < 1e-8f) ? 0.0f : pitch;
    }
}

extern "C" void kernel_launch(void* const* d_in, const int* in_sizes, int n_in,
                              void* d_out, int out_size, void* d_ws, size_t ws_size,
                              hipStream_t stream) {
    const float* audio = (const float*)d_in[0];
    float* out = (float*)d_out;
    pitch_kernel<<<dim3(512), dim3(256), 0, stream>>>(audio, out);
}

// Round 7
// 96.439 us; speedup vs baseline: 1.0597x; 1.0597x over previous
//
#include <hip/hip_runtime.h>

// SimplePitchEstimator on MI355X (gfx950).
// ac = irfft(rfft(x,512)^2) == linear self-convolution c[n] = sum y[i]y[n-i],
// y = x - mean(x). Round-18: RESTORE r16 (verified best, 95.54us).
//
// Evidence chain: r12 = 97.17us = 2x ~42.5us harness poison fills
// (immutable) + ~12.1us kernel. r15 (pk_fma even half) -> 96.15; r16
// (dual-bank full packing) -> 95.54; both matched prediction. Kernel
// ~10.5us = 6.7 HBM (exact mandatory fetch) + ~3.3 conv (fully packed)
// + ~0.5 phases, serial.
// OVERLAP LEDGER CLOSED — three mechanisms, three regressions:
//   r13 cross-block s_sleep stagger  +3.9us (dispatch mapping undefined)
//   r14 register-staged 2-pass       +6.7us (vmcnt at drain + VGPR bloat
//                                            + 2-block/CU starvation)
//   r17 LDS dbuf via global_load_lds +6.7us (2x40960 B = exactly the
//        160KiB pool -> occupancy halves: 1 block/CU or 1 wave/SIMD;
//        DMA overlap < occupancy loss)
// The double-buffer needs 2x frame storage by construction and 2x40960
// does not co-reside; no fourth mechanism avoids all three failure modes.
// Remaining total = ~85us fills + ~10.5us kernel; floor ~91.7 (85+6.7).
// This restore is the terminal kernel: predicted 95.3-95.8, absmax 0.0.
//
//  * Bank A: lag-pairs (0,1)..(12,13)+scalar j14 (even-parity d's);
//    Bank B: pairs (1,2)..(13,14)+scalar j0 (odd-parity d's); clean round
//    = 4 x (7 v_pk_fma_f32 + 1 fma) = 32 issue slots (vs 60 scalar).
//    Finalize acc[j] = A[j]+B[j] (d-parity regroup, ~ulp; argmax robust).
//  * Twelve NAMED f32x2 vars P0..P11 = 6 window quads as aligned halves;
//    rotation map (quad % 6) repeats every 6 rounds; all refs static.
//  * Refill ds_read_b128 -> two f32x2 splits into rotating target vars,
//    placed after the round's FMAs; x quads via 2-var ping-pong.
//  * Ragged rounds statically unrolled, scalar bank-A, masks 8r+2d<N0+j.
//  * Half-sum c[n] = 2*sum_{2i<n} y_i y_{n-i} + center (validated r6-r10).
//  * LDS 160x64x4 = 40960 B exactly (4 blocks/CU, 1024 blocks co-resident);
//    balanced tile pairs 27/27/28/28; mu folded at LDS write; silent-check
//    pm rides in a register to the final reduction.

#define SR_F    16000.0f
#define HOPSZ   256
#define TFRAMES 4096
#define SAMPLES 1048576

typedef __attribute__((ext_vector_type(2))) float f32x2;

#define CMP(v_, c_) ((c_) == 0 ? (v_).x : (c_) == 1 ? (v_).y : \
                     (c_) == 2 ? (v_).z : (v_).w)

template<int N0>
__device__ __forceinline__ void conv_tile(const float4* __restrict__ col4,
                                          const float* __restrict__ colf,
                                          float& best, int& bl) {
    constexpr int J    = 15;
    constexpr int B0   = ((N0 - 3) / 4) * 4;   // aligned window base row
    constexpr int Q0   = B0 / 4;               // base quad at round 0
    constexpr int KOFF = N0 - B0;              // 3..6
    constexpr int IC   = (N0 + J) / 2;         // i-count for max lag
    constexpr int RT   = (IC + 3) / 4;         // total rounds
    constexpr int RC   = (N0 - 6 + 7) / 8;     // clean rounds (8r+6 < N0)
    constexpr int T    = RC / 6;               // runtime x6 trips
    constexpr int R6   = 6 * T;                // first static round
    static_assert(KOFF >= 3 && KOFF + J - 1 <= 20, "window index bound");
    static_assert(RC >= 1 && RC <= RT - 1, "clean/ragged split");
    static_assert(Q0 - RT + 1 >= 0, "refill quad in range");

    // Bank A: pairs (0,1)(2,3)...(12,13) + scalar j=14  (even-parity d's)
    // Bank B: pairs (1,2)(3,4)...(13,14) + scalar j=0   (odd-parity d's)
    // final acc[j] = A[j] + B[j]; regrouping by d-parity only.
    f32x2 accA[7], accB[7];
    float accA14 = 0.f, accB0 = 0.f;
    #pragma unroll
    for (int p = 0; p < 7; ++p) { accA[p] = f32x2{0.f, 0.f};
                                  accB[p] = f32x2{0.f, 0.f}; }

    // window: quad-var vi (0..5) -> pair vars (2vi, 2vi+1)
    f32x2 P0_, P1_, P2_, P3_, P4_, P5_, P6_, P7_, P8_, P9_, P10_, P11_;
    float4 xa_, xb_;

#define PPAIR(pi_) \
    ((pi_) == 0 ? P0_ : (pi_) == 1 ? P1_ : (pi_) == 2 ? P2_ :  \
     (pi_) == 3 ? P3_ : (pi_) == 4 ? P4_ : (pi_) == 5 ? P5_ :  \
     (pi_) == 6 ? P6_ : (pi_) == 7 ? P7_ : (pi_) == 8 ? P8_ :  \
     (pi_) == 9 ? P9_ : (pi_) == 10 ? P10_ : P11_)

#define PREAD(pi_, h_) ((h_) ? PPAIR(pi_).y : PPAIR(pi_).x)

#define PST(pi_, e_) do {                                                 \
    if      ((pi_) == 0)  P0_  = (e_); else if ((pi_) == 1)  P1_  = (e_); \
    else if ((pi_) == 2)  P2_  = (e_); else if ((pi_) == 3)  P3_  = (e_); \
    else if ((pi_) == 4)  P4_  = (e_); else if ((pi_) == 5)  P5_  = (e_); \
    else if ((pi_) == 6)  P6_  = (e_); else if ((pi_) == 7)  P7_  = (e_); \
    else if ((pi_) == 8)  P8_  = (e_); else if ((pi_) == 9)  P9_  = (e_); \
    else if ((pi_) == 10) P10_ = (e_); else                  P11_ = (e_); \
    } while (0)

#define WSTORE(vi_, q_) do {                                              \
    PST(2 * (vi_),     (f32x2{(q_).x, (q_).y}));                          \
    PST(2 * (vi_) + 1, (f32x2{(q_).z, (q_).w}));                          \
    } while (0)

    // round with round-index R_ (mask/parity) and rotation phase K_ (=R_ mod 6
    // folded statically); MASKED_=1 -> ragged prune, all-scalar into bank A.
    // Clean rounds: even-parity d -> bank A pairs (g = KOFF+2p-d even);
    //               odd-parity d  -> bank B pairs (g = KOFF+2p+1-d even).
#define ROUND_BODY(K_, R_, MASKED_)                                       \
    {                                                                     \
        const float4 xc = ((R_) & 1) ? xb_ : xa_;                         \
        _Pragma("unroll")                                                 \
        for (int d = 0; d < 4; ++d) {                                     \
            const float xv = CMP(xc, d);                                  \
            if (!(MASKED_) && (((KOFF - d) & 1) == 0)) {                  \
                const f32x2 xv2 = {xv, xv};                               \
                _Pragma("unroll")                                         \
                for (int p = 0; p < 7; ++p) {                             \
                    const int g  = KOFF + 2 * p - d;       /* even */     \
                    const int vi = ((Q0 + g / 4 - (K_)) % 6 + 6) % 6;     \
                    const int pi = 2 * vi + ((g >> 1) & 1);               \
                    accA[p] = __builtin_elementwise_fma(xv2, PPAIR(pi),   \
                                                        accA[p]);         \
                }                                                         \
                {                                                         \
                    const int g  = KOFF + 14 - d;                         \
                    const int vi = ((Q0 + g / 4 - (K_)) % 6 + 6) % 6;     \
                    const int pi = 2 * vi + ((g >> 1) & 1);               \
                    accA14 = fmaf(xv, PREAD(pi, g & 1), accA14);          \
                }                                                         \
            } else if (!(MASKED_)) {                                      \
                const f32x2 xv2 = {xv, xv};                               \
                {                                                         \
                    const int g  = KOFF + 0 - d;           /* even */     \
                    const int vi = ((Q0 + g / 4 - (K_)) % 6 + 6) % 6;     \
                    const int pi = 2 * vi + ((g >> 1) & 1);               \
                    accB0 = fmaf(xv, PREAD(pi, g & 1), accB0);            \
                }                                                         \
                _Pragma("unroll")                                         \
                for (int p = 0; p < 7; ++p) {                             \
                    const int g  = KOFF + 2 * p + 1 - d;   /* even */     \
                    const int vi = ((Q0 + g / 4 - (K_)) % 6 + 6) % 6;     \
                    const int pi = 2 * vi + ((g >> 1) & 1);               \
                    accB[p] = __builtin_elementwise_fma(xv2, PPAIR(pi),   \
                                                        accB[p]);         \
                }                                                         \
            } else {                                                      \
                _Pragma("unroll")                                         \
                for (int j = 0; j < J; ++j) {                             \
                    if (8 * (R_) + 2 * d < N0 + j) {                      \
                        const int g  = KOFF + j - d;                      \
                        const int vi = ((Q0 + g / 4 - (K_)) % 6 + 6) % 6; \
                        const int pi = 2 * vi + ((g >> 1) & 1);           \
                        const float wv = PREAD(pi, g & 1);                \
                        if (j == 14)                                      \
                            accA14 = fmaf(xv, wv, accA14);                \
                        else if (j & 1)                                   \
                            accA[j >> 1].y = fmaf(xv, wv, accA[j >> 1].y);\
                        else                                              \
                            accA[j >> 1].x = fmaf(xv, wv, accA[j >> 1].x);\
                    }                                                     \
                }                                                         \
            }                                                             \
        }                                                                 \
    }

    // ---- init: quads Q0..Q0+5 into vars (Q0+i)%6 (clip quads>39), x quad 0
    #pragma unroll
    for (int i = 0; i < 6; ++i) {
        const float4 q = (Q0 + i <= 39) ? col4[(Q0 + i) * 64]
                                        : make_float4(0.f, 0.f, 0.f, 0.f);
        WSTORE((Q0 + i) % 6, q);
    }
    xa_ = col4[0];

    // ---- runtime x6 trips: rounds r = 6t+k, all clean ----
    const float4* xq = col4;                 // x base: quad 6t
    const float4* wq = col4 + Q0 * 64;       // refill base: quad Q0-6t
    #pragma unroll 1
    for (int t = 0; t < T; ++t) {
        #pragma unroll
        for (int k = 0; k < 6; ++k) {
            if (((k + 1) & 1) == 0) xa_ = xq[(k + 1) * 64];
            else                    xb_ = xq[(k + 1) * 64];
            ROUND_BODY(k, k, 0)
            // refill quad Q0-6t-k-1 -> var just freed this round
            {
                const float4 rq = wq[-(k + 1) * 64];
                WSTORE(((Q0 - k - 1) % 6 + 6) % 6, rq);
            }
        }
        xq += 6 * 64;
        wq -= 6 * 64;
    }

    // ---- static rounds rr = R6..RT-1 (clean remainder + ragged) ----
    #pragma unroll
    for (int u = 0; u < RT - R6; ++u) {
        const int rr = R6 + u;                       // constant after unroll
        if (rr + 1 < RT) {                           // compile-time guard
            if (((rr + 1) & 1) == 0) xa_ = col4[(rr + 1) * 64];
            else                     xb_ = col4[(rr + 1) * 64];
        }
        ROUND_BODY(rr, rr, (rr >= RC))
        if (rr + 1 < RT) {
            const float4 rq = col4[(Q0 - rr - 1) * 64];
            WSTORE(((Q0 - rr - 1) % 6 + 6) % 6, rq);
        }
    }

    // ---- finalize: combine banks, x2 + center term, local argmax ----
    // A[j]: j=14 -> accA14; else lane (j&1) of accA[j>>1].
    // B[j]: j=0 -> accB0; j odd -> accB[(j-1)/2].x; j even -> accB[j/2-1].y.
    #pragma unroll
    for (int j = 0; j < J; ++j) {
        const float av = (j == 14) ? accA14
                        : ((j & 1) ? accA[j >> 1].y : accA[j >> 1].x);
        const float bv2 = (j == 0) ? accB0
                        : ((j & 1) ? accB[(j - 1) >> 1].x : accB[j / 2 - 1].y);
        const float aj = av + bv2;
        float v2 = aj + aj;
        if ((N0 + j) % 2 == 0) {
            const int R = (N0 + j) / 2;              // constant after unroll
            const float c = colf[(R / 4) * 256 + (R & 3)];
            v2 = fmaf(c, c, v2);
        }
        if (v2 > best) { best = v2; bl = N0 + j; }   // strict >: first max
    }
#undef ROUND_BODY
#undef WSTORE
#undef PST
#undef PREAD
#undef PPAIR
}

__global__ __launch_bounds__(256)
void pitch_kernel(const float* __restrict__ audio, float* __restrict__ out) {
    __shared__ float4 X4[40 * 64];                   // 40960 B exactly
    float* Xa = reinterpret_cast<float*>(X4);

    const int tid = threadIdx.x;
    const int s   = tid >> 6;          // wave id
    const int f   = tid & 63;          // frame within block
    const int blk = blockIdx.x;
    const int b   = blk >> 6;          // batch row
    const int t0  = (blk & 63) << 6;   // first frame of block

    // ---- Phase A: load 40 samples of frame f (chunk s), partial sum ----
    const float* g = audio + (size_t)b * SAMPLES + (size_t)(t0 + f) * HOPSZ + s * 40;
    float v[40];
    float ps = 0.f;
    #pragma unroll
    for (int j = 0; j < 10; ++j) {
        float4 q = reinterpret_cast<const float4*>(g)[j];   // 16B-aligned
        v[4*j+0] = q.x; v[4*j+1] = q.y; v[4*j+2] = q.z; v[4*j+3] = q.w;
        ps += q.x + q.y + q.z + q.w;
    }

    // ---- Phase B: block mean via aux rows; pm stays in a register ----
    Xa[s * 64 + f] = ps;
    __syncthreads();
    const float mu = (Xa[f] + Xa[64 + f] + Xa[128 + f] + Xa[192 + f]) * (1.0f / 160.0f);
    // center in place; pm = max|c| via fmax(c,-c) (v_max3 w/ neg modifier)
    #pragma unroll
    for (int q = 0; q < 40; ++q) v[q] = v[q] - mu;
    float pm = 0.f;
    #pragma unroll
    for (int q = 0; q < 40; ++q) pm = fmaxf(pm, fmaxf(v[q], -v[q]));
    __syncthreads();                       // sum-reads done before D overwrites

    // ---- Phase D: write centered frames as row-quads (b128, contiguous) ----
    #pragma unroll
    for (int k = 0; k < 10; ++k)
        X4[(10 * s + k) * 64 + f] =
            make_float4(v[4*k+0], v[4*k+1], v[4*k+2], v[4*k+3]);
    __syncthreads();

    // ---- Phase E: paired balanced tiles (rounds 27/27/28/28) ----
    const float4* col4 = X4 + f;
    const float*  colf = Xa + 4 * f;
    float best = -3.4e38f; int bl = 0;
    if      (s == 0) { conv_tile< 40>(col4, colf, best, bl);
                       conv_tile<145>(col4, colf, best, bl); }
    else if (s == 1) { conv_tile< 55>(col4, colf, best, bl);
                       conv_tile<130>(col4, colf, best, bl); }
    else if (s == 2) { conv_tile< 70>(col4, colf, best, bl);
                       conv_tile<115>(col4, colf, best, bl); }
    else             { conv_tile< 85>(col4, colf, best, bl);
                       conv_tile<100>(col4, colf, best, bl); }
    __syncthreads();                       // conv done: X now dead

    // ---- Phase F: cross-wave argmax + silent-check via aux rows ----
    Xa[s * 64 + f] = best;
    reinterpret_cast<int*>(Xa)[256 + s * 64 + f] = bl;
    Xa[512 + s * 64 + f] = pm;
    __syncthreads();

    if (s == 0) {
        float bv = Xa[f];
        int   L  = reinterpret_cast<int*>(Xa)[256 + f];
        #pragma unroll
        for (int c = 1; c < 4; ++c) {
            const float vv = Xa[c * 64 + f];
            const int   lv = reinterpret_cast<int*>(Xa)[256 + c * 64 + f];
            if (vv > bv || (vv == bv && lv < L)) { bv = vv; L = lv; }
        }
        const float mx = fmaxf(fmaxf(Xa[512 + f], Xa[512 + 64 + f]),
                               fmaxf(Xa[512 + 128 + f], Xa[512 + 192 + f]));
        const float pitch = SR_F / (float)L;
        out[(size_t)b * TFRAMES + t0 + f] = (mx < 1e-8f) ? 0.0f : pitch;
    }
}

extern "C" void kernel_launch(void* const* d_in, const int* in_sizes, int n_in,
                              void* d_out, int out_size, void* d_ws, size_t ws_size,
                              hipStream_t stream) {
    const float* audio = (const float*)d_in[0];
    float* out = (float*)d_out;
    pitch_kernel<<<dim3(1024), dim3(256), 0, stream>>>(audio, out);
}